// Round 1
// baseline (343.967 us; speedup 1.0000x reference)
//
#include <hip/hip_runtime.h>
#include <hip/hip_bf16.h>

#define D_MODEL 1024
#define NUM_HEADS 16
#define HEAD_DIM 64
#define BATCH 2
#define SEQ 2048
#define M_TOT (BATCH*SEQ)      // 4096
#define CHUNK 64
#define NCHUNK (SEQ/CHUNK)     // 32

typedef __attribute__((ext_vector_type(8))) short bf16x8;
typedef __attribute__((ext_vector_type(4))) float f32x4;

__device__ inline ushort f2bf(float f) {
    __hip_bfloat16 h = __float2bfloat16(f);
    return __builtin_bit_cast(ushort, h);
}

// ---------------- cast fp32 -> bf16 (4 elems/thread, exact grid) ----------------
__global__ __launch_bounds__(256) void cast_bf16_kernel(const float* __restrict__ in,
                                                        ushort* __restrict__ out) {
    int i = blockIdx.x * blockDim.x + threadIdx.x;
    float4 f = ((const float4*)in)[i];
    ushort4 u;
    u.x = f2bf(f.x); u.y = f2bf(f.y); u.z = f2bf(f.z); u.w = f2bf(f.w);
    ((ushort4*)out)[i] = u;
}

// ---------------- decay table: decay[i*16+h] = gamma[h]^i ----------------
__global__ __launch_bounds__(256) void decay_kernel(const float* __restrict__ gamma,
                                                    float* __restrict__ decay) {
    int idx = blockIdx.x * blockDim.x + threadIdx.x;   // SEQ*NUM_HEADS = 32768
    if (idx < SEQ * NUM_HEADS) {
        int i = idx >> 4, h = idx & 15;
        decay[idx] = powf(gamma[h], (float)i);
    }
}

// ---------------- bf16 MFMA GEMM: C[m,n] = sum_k A[m,k]*Bt[n,k] + bias[n] ----------------
// grid (N/64, M/64), 256 threads (4 waves), 64x64 tile, BK=32.
// If decay != nullptr: C *= decay[(m % SEQ)*16 + (n>>6)]
__device__ inline bf16x8 ld_frag(const ushort* p) {
    struct S { uint2 a, b; };
    S s;
    s.a = *(const uint2*)p;
    s.b = *(const uint2*)(p + 4);
    return __builtin_bit_cast(bf16x8, s);
}

__global__ __launch_bounds__(256) void gemm_bt(const ushort* __restrict__ A,
                                               const ushort* __restrict__ Bt,
                                               const float* __restrict__ bias,
                                               float* __restrict__ C,
                                               const float* __restrict__ decay) {
    const int K = 1024, N = 1024;
    __shared__ ushort lds_a[64 * 36];
    __shared__ ushort lds_b[64 * 36];
    int t = threadIdx.x;
    int lane = t & 63, w = t >> 6;
    int bm = blockIdx.y * 64, bn = blockIdx.x * 64;
    int wm = (w >> 1) * 32, wn = (w & 1) * 32;
    int r = t >> 2, cc = t & 3;  // staging: row r, 16B chunk cc
    const uint4* gA = (const uint4*)(A + (size_t)(bm + r) * K);
    const uint4* gB = (const uint4*)(Bt + (size_t)(bn + r) * K);
    f32x4 acc[2][2];
    #pragma unroll
    for (int i = 0; i < 2; i++)
        #pragma unroll
        for (int j = 0; j < 2; j++)
            acc[i][j] = (f32x4){0.f, 0.f, 0.f, 0.f};
    int mrel = lane & 15;
    int q8 = (lane >> 4) * 8;

    for (int k0 = 0; k0 < K; k0 += 32) {
        uint4 va = gA[(k0 >> 3) + cc];
        uint4 vb = gB[(k0 >> 3) + cc];
        int so = r * 36 + cc * 8;
        *(uint2*)&lds_a[so]     = make_uint2(va.x, va.y);
        *(uint2*)&lds_a[so + 4] = make_uint2(va.z, va.w);
        *(uint2*)&lds_b[so]     = make_uint2(vb.x, vb.y);
        *(uint2*)&lds_b[so + 4] = make_uint2(vb.z, vb.w);
        __syncthreads();
        bf16x8 af[2], bfr[2];
        #pragma unroll
        for (int i = 0; i < 2; i++)
            af[i] = ld_frag(&lds_a[(wm + i * 16 + mrel) * 36 + q8]);
        #pragma unroll
        for (int j = 0; j < 2; j++)
            bfr[j] = ld_frag(&lds_b[(wn + j * 16 + mrel) * 36 + q8]);
        #pragma unroll
        for (int i = 0; i < 2; i++)
            #pragma unroll
            for (int j = 0; j < 2; j++)
                acc[i][j] = __builtin_amdgcn_mfma_f32_16x16x32_bf16(af[i], bfr[j], acc[i][j], 0, 0, 0);
        __syncthreads();
    }

    // epilogue: C/D layout col = lane&15, row = (lane>>4)*4 + reg
    int row_q = (lane >> 4) * 4;
    int col_in = lane & 15;
    #pragma unroll
    for (int i = 0; i < 2; i++) {
        #pragma unroll
        for (int j = 0; j < 2; j++) {
            int col = bn + wn + j * 16 + col_in;
            #pragma unroll
            for (int rr = 0; rr < 4; rr++) {
                int row = bm + wm + i * 16 + row_q + rr;
                float v = acc[i][j][rr] + bias[col];
                if (decay) v *= decay[(row & (SEQ - 1)) * 16 + (col >> 6)];
                C[(size_t)row * N + col] = v;
            }
        }
    }
}

// ---------------- per-chunk KV state: KV_c[dk][dv] = sum_j k[j][dk]*v[j][dv] ----------------
// grid = B*H*NCHUNK = 1024 blocks, 256 threads. block id = (b*16+h)*32 + c
__global__ __launch_bounds__(256) void chunk_kv_kernel(const float* __restrict__ kp,
                                                       const float* __restrict__ vp,
                                                       float* __restrict__ states) {
    __shared__ float Ks[64 * 65];
    __shared__ float Vs[64 * 65];
    int bx = blockIdx.x;
    int c = bx & 31, h = (bx >> 5) & 15, b = bx >> 9;
    int t = threadIdx.x;
    int jr = t >> 2, g = t & 3;
    size_t rowbase = (size_t)(b * SEQ + c * 64);
    const float* kptr = kp + (rowbase + jr) * D_MODEL + h * 64 + g * 16;
    const float* vptr = vp + (rowbase + jr) * D_MODEL + h * 64 + g * 16;
    #pragma unroll
    for (int rr = 0; rr < 4; rr++) {
        float4 k4 = *(const float4*)(kptr + rr * 4);
        float4 v4 = *(const float4*)(vptr + rr * 4);
        int off = jr * 65 + g * 16 + rr * 4;
        Ks[off + 0] = k4.x; Ks[off + 1] = k4.y; Ks[off + 2] = k4.z; Ks[off + 3] = k4.w;
        Vs[off + 0] = v4.x; Vs[off + 1] = v4.y; Vs[off + 2] = v4.z; Vs[off + 3] = v4.w;
    }
    __syncthreads();
    int dk = t >> 2;
    float acc[16];
    #pragma unroll
    for (int rr = 0; rr < 16; rr++) acc[rr] = 0.f;
    for (int j = 0; j < 64; j++) {
        float kv = Ks[j * 65 + dk];
        #pragma unroll
        for (int rr = 0; rr < 16; rr++) acc[rr] += kv * Vs[j * 65 + g * 16 + rr];
    }
    float* sp = states + (size_t)bx * 4096 + dk * 64 + g * 16;
    #pragma unroll
    for (int rr = 0; rr < 16; rr++) sp[rr] = acc[rr];
}

// ---------------- exclusive prefix over chunks, per (b,h) ----------------
__global__ __launch_bounds__(256) void prefix_kernel(float* __restrict__ states) {
    int bh = blockIdx.x;  // 32
    int t = threadIdx.x;
    float run[16];
    #pragma unroll
    for (int rr = 0; rr < 16; rr++) run[rr] = 0.f;
    float* base = states + (size_t)bh * NCHUNK * 4096 + t * 16;
    for (int c = 0; c < NCHUNK; c++) {
        float* p = base + (size_t)c * 4096;
        #pragma unroll
        for (int rr = 0; rr < 16; rr++) {
            float tmp = p[rr];
            p[rr] = run[rr];
            run[rr] += tmp;
        }
    }
}

// ---------------- per-chunk attention: out = Q'·S_pre + causal(Q'K^T)·V ----------------
// grid = 1024 blocks ((b*16+h)*32 + c), 256 threads.
__global__ __launch_bounds__(256) void attn_chunk_kernel(const float* __restrict__ qp,
                                                         const float* __restrict__ kp,
                                                         const float* __restrict__ vp,
                                                         const float* __restrict__ states,
                                                         float* __restrict__ attn) {
    __shared__ float Qs[64 * 65];
    __shared__ float Ks[64 * 65];   // K, later reused for V
    __shared__ float Ss[64 * 65];   // S_pre, later reused for P
    int bx = blockIdx.x;
    int c = bx & 31, h = (bx >> 5) & 15, b = bx >> 9;
    int t = threadIdx.x;
    int i = t >> 2, g = t & 3;
    size_t rowbase = (size_t)(b * SEQ + c * 64);

    // load Q', K
    {
        const float* qptr = qp + (rowbase + i) * D_MODEL + h * 64 + g * 16;
        const float* kptr = kp + (rowbase + i) * D_MODEL + h * 64 + g * 16;
        #pragma unroll
        for (int rr = 0; rr < 4; rr++) {
            float4 q4 = *(const float4*)(qptr + rr * 4);
            float4 k4 = *(const float4*)(kptr + rr * 4);
            int off = i * 65 + g * 16 + rr * 4;
            Qs[off + 0] = q4.x; Qs[off + 1] = q4.y; Qs[off + 2] = q4.z; Qs[off + 3] = q4.w;
            Ks[off + 0] = k4.x; Ks[off + 1] = k4.y; Ks[off + 2] = k4.z; Ks[off + 3] = k4.w;
        }
        // load S (4096 floats): thread t owns 16 consecutive -> dk = t>>2, dv = (t&3)*16
        const float* sp = states + (size_t)bx * 4096 + t * 16;
        #pragma unroll
        for (int rr = 0; rr < 16; rr++)
            Ss[(t >> 2) * 65 + (t & 3) * 16 + rr] = sp[rr];
    }
    __syncthreads();

    float acc[16];
    #pragma unroll
    for (int rr = 0; rr < 16; rr++) acc[rr] = 0.f;

    // inter-chunk: acc += Q'[i]·S
    for (int dk = 0; dk < 64; dk++) {
        float qv = Qs[i * 65 + dk];
        #pragma unroll
        for (int rr = 0; rr < 16; rr++) acc[rr] += qv * Ss[dk * 65 + g * 16 + rr];
    }
    __syncthreads();   // everyone done reading S

    // intra phase a: P[i][j] for j = g + 4*jj, causal-masked; store into Ss
    {
        float p[16];
        #pragma unroll
        for (int jj = 0; jj < 16; jj++) p[jj] = 0.f;
        for (int dd = 0; dd < 64; dd++) {
            float qv = Qs[i * 65 + dd];
            #pragma unroll
            for (int jj = 0; jj < 16; jj++) p[jj] += qv * Ks[(g + 4 * jj) * 65 + dd];
        }
        #pragma unroll
        for (int jj = 0; jj < 16; jj++) {
            int j = g + 4 * jj;
            if (j > i) p[jj] = 0.f;
            Ss[i * 65 + j] = p[jj];
        }
    }
    __syncthreads();   // everyone done reading K (and P fully written)

    // load V into Ks slot
    {
        const float* vptr = vp + (rowbase + i) * D_MODEL + h * 64 + g * 16;
        #pragma unroll
        for (int rr = 0; rr < 4; rr++) {
            float4 v4 = *(const float4*)(vptr + rr * 4);
            int off = i * 65 + g * 16 + rr * 4;
            Ks[off + 0] = v4.x; Ks[off + 1] = v4.y; Ks[off + 2] = v4.z; Ks[off + 3] = v4.w;
        }
    }
    __syncthreads();

    // intra phase b: acc += P[i][j]·V[j]
    for (int j = 0; j < 64; j++) {
        float pv = Ss[i * 65 + j];
        #pragma unroll
        for (int rr = 0; rr < 16; rr++) acc[rr] += pv * Ks[j * 65 + g * 16 + rr];
    }

    float* op = attn + (rowbase + i) * D_MODEL + h * 64 + g * 16;
    #pragma unroll
    for (int rr = 0; rr < 4; rr++) {
        float4 o4;
        o4.x = acc[rr * 4 + 0]; o4.y = acc[rr * 4 + 1];
        o4.z = acc[rr * 4 + 2]; o4.w = acc[rr * 4 + 3];
        *(float4*)(op + rr * 4) = o4;
    }
}

// ---------------- host launch ----------------
extern "C" void kernel_launch(void* const* d_in, const int* in_sizes, int n_in,
                              void* d_out, int out_size, void* d_ws, size_t ws_size,
                              hipStream_t stream) {
    (void)in_sizes; (void)n_in; (void)out_size; (void)ws_size;
    const float* x  = (const float*)d_in[0];
    const float* Wq = (const float*)d_in[1];
    const float* bq = (const float*)d_in[2];
    const float* Wk = (const float*)d_in[3];
    const float* bk = (const float*)d_in[4];
    const float* Wv = (const float*)d_in[5];
    const float* bv = (const float*)d_in[6];
    const float* Wo = (const float*)d_in[7];
    const float* bo = (const float*)d_in[8];
    const float* gamma = (const float*)d_in[9];
    float* out = (float*)d_out;

    // workspace carve-up
    uint8_t* w = (uint8_t*)d_ws;
    ushort* xb  = (ushort*)w; w += (size_t)M_TOT * D_MODEL * 2;       // 8 MB (reused for attn bf16)
    ushort* wqb = (ushort*)w; w += (size_t)D_MODEL * D_MODEL * 2;     // 2 MB
    ushort* wkb = (ushort*)w; w += (size_t)D_MODEL * D_MODEL * 2;
    ushort* wvb = (ushort*)w; w += (size_t)D_MODEL * D_MODEL * 2;
    ushort* wob = (ushort*)w; w += (size_t)D_MODEL * D_MODEL * 2;
    float* qp     = (float*)w; w += (size_t)M_TOT * D_MODEL * 4;      // 16 MB
    float* kp     = (float*)w; w += (size_t)M_TOT * D_MODEL * 4;
    float* vp     = (float*)w; w += (size_t)M_TOT * D_MODEL * 4;
    float* states = (float*)w; w += (size_t)BATCH * NUM_HEADS * NCHUNK * 4096 * 4; // 16 MB
    float* attn   = (float*)w; w += (size_t)M_TOT * D_MODEL * 4;      // 16 MB
    float* decay  = (float*)w; w += (size_t)SEQ * NUM_HEADS * 4;      // 128 KB

    // casts
    cast_bf16_kernel<<<(M_TOT * D_MODEL) / 4 / 256, 256, 0, stream>>>(x, xb);
    cast_bf16_kernel<<<(D_MODEL * D_MODEL) / 4 / 256, 256, 0, stream>>>(Wq, wqb);
    cast_bf16_kernel<<<(D_MODEL * D_MODEL) / 4 / 256, 256, 0, stream>>>(Wk, wkb);
    cast_bf16_kernel<<<(D_MODEL * D_MODEL) / 4 / 256, 256, 0, stream>>>(Wv, wvb);
    cast_bf16_kernel<<<(D_MODEL * D_MODEL) / 4 / 256, 256, 0, stream>>>(Wo, wob);
    decay_kernel<<<(SEQ * NUM_HEADS) / 256, 256, 0, stream>>>(gamma, decay);

    dim3 ggrid(D_MODEL / 64, M_TOT / 64);   // (16, 64)
    gemm_bt<<<ggrid, 256, 0, stream>>>(xb, wqb, bq, qp, decay);    // q' = (xWq^T+bq)*gamma^i
    gemm_bt<<<ggrid, 256, 0, stream>>>(xb, wkb, bk, kp, nullptr);
    gemm_bt<<<ggrid, 256, 0, stream>>>(xb, wvb, bv, vp, nullptr);

    int nblk = BATCH * NUM_HEADS * NCHUNK;  // 1024
    chunk_kv_kernel<<<nblk, 256, 0, stream>>>(kp, vp, states);
    prefix_kernel<<<BATCH * NUM_HEADS, 256, 0, stream>>>(states);
    attn_chunk_kernel<<<nblk, 256, 0, stream>>>(qp, kp, vp, states, attn);

    // cast attn -> bf16 (reuse xb), output projection
    cast_bf16_kernel<<<(M_TOT * D_MODEL) / 4 / 256, 256, 0, stream>>>(attn, xb);
    gemm_bt<<<ggrid, 256, 0, stream>>>(xb, wob, bo, out, nullptr);
}

// Round 2
// 223.498 us; speedup vs baseline: 1.5390x; 1.5390x over previous
//
#include <hip/hip_runtime.h>
#include <hip/hip_bf16.h>

#define D_MODEL 1024
#define NUM_HEADS 16
#define HEAD_DIM 64
#define BATCH 2
#define SEQ 2048
#define M_TOT (BATCH*SEQ)      // 4096
#define CHUNK 64
#define NCHUNK (SEQ/CHUNK)     // 32
#define LT 68                  // LDS tile stride in ushorts (136B: 8B-aligned rows, spread banks)

typedef __attribute__((ext_vector_type(8))) short bf16x8;
typedef __attribute__((ext_vector_type(8))) unsigned short us16x8;
typedef __attribute__((ext_vector_type(4))) float f32x4;

__device__ inline ushort f2bf(float f) {
    __hip_bfloat16 h = __float2bfloat16(f);
    return __builtin_bit_cast(ushort, h);
}

__device__ inline bf16x8 ld_frag(const ushort* p) {
    struct S { uint2 a, b; };
    S s;
    s.a = *(const uint2*)p;
    s.b = *(const uint2*)(p + 4);
    return __builtin_bit_cast(bf16x8, s);
}

// store 16 ushorts (two uint4) to 8B-aligned LDS
__device__ inline void st16(ushort* dst, uint4 a, uint4 b) {
    *(uint2*)(dst + 0)  = make_uint2(a.x, a.y);
    *(uint2*)(dst + 4)  = make_uint2(a.z, a.w);
    *(uint2*)(dst + 8)  = make_uint2(b.x, b.y);
    *(uint2*)(dst + 12) = make_uint2(b.z, b.w);
}

// ---------------- cast fp32 -> bf16 (4 elems/thread, exact grid) ----------------
__global__ __launch_bounds__(256) void cast_bf16_kernel(const float* __restrict__ in,
                                                        ushort* __restrict__ out) {
    int i = blockIdx.x * blockDim.x + threadIdx.x;
    float4 f = ((const float4*)in)[i];
    ushort4 u;
    u.x = f2bf(f.x); u.y = f2bf(f.y); u.z = f2bf(f.z); u.w = f2bf(f.w);
    ((ushort4*)out)[i] = u;
}

// ---------------- decay table: decay[i*16+h] = gamma[h]^i ----------------
__global__ __launch_bounds__(256) void decay_kernel(const float* __restrict__ gamma,
                                                    float* __restrict__ decay) {
    int idx = blockIdx.x * blockDim.x + threadIdx.x;   // SEQ*NUM_HEADS = 32768
    if (idx < SEQ * NUM_HEADS) {
        int i = idx >> 4, h = idx & 15;
        decay[idx] = powf(gamma[h], (float)i);
    }
}

// ---------------- bf16 MFMA GEMM: C[m,n] = sum_k A[m,k]*Bt[n,k] + bias[n] ----------------
// grid (N/64, M/64), 256 threads (4 waves), 64x64 tile, BK=32.
// If decay != nullptr: C *= decay[(m % SEQ)*16 + (n>>6)]
// OUT_BF16: write ushort bf16, else float.
template <int OUT_BF16>
__global__ __launch_bounds__(256) void gemm_bt(const ushort* __restrict__ A,
                                               const ushort* __restrict__ Bt,
                                               const float* __restrict__ bias,
                                               void* __restrict__ Cv,
                                               const float* __restrict__ decay) {
    const int K = 1024, N = 1024;
    __shared__ ushort lds_a[64 * 36];
    __shared__ ushort lds_b[64 * 36];
    int t = threadIdx.x;
    int lane = t & 63, w = t >> 6;
    int bm = blockIdx.y * 64, bn = blockIdx.x * 64;
    int wm = (w >> 1) * 32, wn = (w & 1) * 32;
    int r = t >> 2, cc = t & 3;  // staging: row r, 16B chunk cc
    const uint4* gA = (const uint4*)(A + (size_t)(bm + r) * K);
    const uint4* gB = (const uint4*)(Bt + (size_t)(bn + r) * K);
    f32x4 acc[2][2];
    #pragma unroll
    for (int i = 0; i < 2; i++)
        #pragma unroll
        for (int j = 0; j < 2; j++)
            acc[i][j] = (f32x4){0.f, 0.f, 0.f, 0.f};
    int mrel = lane & 15;
    int q8 = (lane >> 4) * 8;

    for (int k0 = 0; k0 < K; k0 += 32) {
        uint4 va = gA[(k0 >> 3) + cc];
        uint4 vb = gB[(k0 >> 3) + cc];
        int so = r * 36 + cc * 8;
        *(uint2*)&lds_a[so]     = make_uint2(va.x, va.y);
        *(uint2*)&lds_a[so + 4] = make_uint2(va.z, va.w);
        *(uint2*)&lds_b[so]     = make_uint2(vb.x, vb.y);
        *(uint2*)&lds_b[so + 4] = make_uint2(vb.z, vb.w);
        __syncthreads();
        bf16x8 af[2], bfr[2];
        #pragma unroll
        for (int i = 0; i < 2; i++)
            af[i] = ld_frag(&lds_a[(wm + i * 16 + mrel) * 36 + q8]);
        #pragma unroll
        for (int j = 0; j < 2; j++)
            bfr[j] = ld_frag(&lds_b[(wn + j * 16 + mrel) * 36 + q8]);
        #pragma unroll
        for (int i = 0; i < 2; i++)
            #pragma unroll
            for (int j = 0; j < 2; j++)
                acc[i][j] = __builtin_amdgcn_mfma_f32_16x16x32_bf16(af[i], bfr[j], acc[i][j], 0, 0, 0);
        __syncthreads();
    }

    // epilogue: C/D layout col = lane&15, row = (lane>>4)*4 + reg
    int row_q = (lane >> 4) * 4;
    int col_in = lane & 15;
    #pragma unroll
    for (int i = 0; i < 2; i++) {
        #pragma unroll
        for (int j = 0; j < 2; j++) {
            int col = bn + wn + j * 16 + col_in;
            #pragma unroll
            for (int rr = 0; rr < 4; rr++) {
                int row = bm + wm + i * 16 + row_q + rr;
                float v = acc[i][j][rr] + bias[col];
                if (decay) v *= decay[(row & (SEQ - 1)) * 16 + (col >> 6)];
                if (OUT_BF16)
                    ((ushort*)Cv)[(size_t)row * N + col] = f2bf(v);
                else
                    ((float*)Cv)[(size_t)row * N + col] = v;
            }
        }
    }
}

// ---------------- per-chunk KV state (MFMA): St[dv][dk] = sum_j V[j][dv]*K[j][dk] ----------------
// grid = B*H*NCHUNK = 1024 blocks ((b*16+h)*32 + c), 256 threads (4 waves).
__global__ __launch_bounds__(256) void chunk_kv_mfma(const ushort* __restrict__ kp,
                                                     const ushort* __restrict__ vp,
                                                     float* __restrict__ states) {
    __shared__ ushort Kt[64 * LT];
    __shared__ ushort Vt[64 * LT];
    int bx = blockIdx.x;
    int c = bx & 31, h = (bx >> 5) & 15, b = bx >> 9;
    int t = threadIdx.x, lane = t & 63, w = t >> 6;
    size_t rowbase = (size_t)(b * SEQ + c * 64);
    int r = t >> 2, cc = t & 3;
    const uint4* gk = (const uint4*)(kp + (rowbase + r) * D_MODEL + h * 64 + cc * 16);
    const uint4* gv = (const uint4*)(vp + (rowbase + r) * D_MODEL + h * 64 + cc * 16);
    uint4 k0 = gk[0], k1 = gk[1], v0 = gv[0], v1 = gv[1];
    // transpose scatter: element (row r, col cc*16+i) -> [col][r]
    {
        us16x8 ka = __builtin_bit_cast(us16x8, k0), kb = __builtin_bit_cast(us16x8, k1);
        us16x8 va = __builtin_bit_cast(us16x8, v0), vb = __builtin_bit_cast(us16x8, v1);
        #pragma unroll
        for (int i = 0; i < 8; i++) {
            Kt[(cc * 16 + i) * LT + r]     = ka[i];
            Kt[(cc * 16 + 8 + i) * LT + r] = kb[i];
            Vt[(cc * 16 + i) * LT + r]     = va[i];
            Vt[(cc * 16 + 8 + i) * LT + r] = vb[i];
        }
    }
    __syncthreads();
    int mrel = lane & 15, q8 = (lane >> 4) * 8, band = w * 16;
    bf16x8 af[2];
    af[0] = ld_frag(&Vt[(band + mrel) * LT + q8]);
    af[1] = ld_frag(&Vt[(band + mrel) * LT + 32 + q8]);
    f32x4 acc[4];
    #pragma unroll
    for (int dt = 0; dt < 4; dt++) acc[dt] = (f32x4){0.f, 0.f, 0.f, 0.f};
    #pragma unroll
    for (int dt = 0; dt < 4; dt++)
        #pragma unroll
        for (int kk = 0; kk < 2; kk++)
            acc[dt] = __builtin_amdgcn_mfma_f32_16x16x32_bf16(
                af[kk], ld_frag(&Kt[(dt * 16 + mrel) * LT + kk * 32 + q8]), acc[dt], 0, 0, 0);
    // write fp32 St: row dv = band + quad*4 + reg, col dk = dt*16 + (lane&15)
    int quad = lane >> 4;
    float* sp = states + (size_t)bx * 4096;
    #pragma unroll
    for (int dt = 0; dt < 4; dt++)
        #pragma unroll
        for (int reg = 0; reg < 4; reg++)
            sp[(band + quad * 4 + reg) * 64 + dt * 16 + mrel] = acc[dt][reg];
}

// ---------------- exclusive prefix over chunks -> bf16 states ----------------
// grid (16, 32): blockIdx.y = bh, each thread scans one of 4096 state elements.
__global__ __launch_bounds__(256) void prefix_kernel(const float* __restrict__ states,
                                                     ushort* __restrict__ statesb) {
    int bh = blockIdx.y;
    int e = blockIdx.x * 256 + threadIdx.x;
    const float* src = states + (size_t)bh * NCHUNK * 4096 + e;
    ushort* dst = statesb + (size_t)bh * NCHUNK * 4096 + e;
    float run = 0.f;
    for (int cb = 0; cb < NCHUNK; cb += 8) {
        float vals[8];
        #pragma unroll
        for (int u = 0; u < 8; u++) vals[u] = src[(size_t)(cb + u) * 4096];
        #pragma unroll
        for (int u = 0; u < 8; u++) {
            dst[(size_t)(cb + u) * 4096] = f2bf(run);
            run += vals[u];
        }
    }
}

// ---------------- per-chunk attention (MFMA): O = Q'·S^T + causal(Q'K^T)·V ----------------
// grid = 1024 blocks ((b*16+h)*32 + c), 256 threads (4 waves). Writes bf16 into attn_out.
__global__ __launch_bounds__(256) void attn_mfma(const ushort* __restrict__ qp,
                                                 const ushort* __restrict__ kp,
                                                 const ushort* __restrict__ vp,
                                                 const ushort* __restrict__ statesb,
                                                 ushort* __restrict__ attn_out) {
    __shared__ ushort Qs[64 * LT];
    __shared__ ushort Ks[64 * LT];
    __shared__ ushort Vt[64 * LT];
    __shared__ ushort St[64 * LT];
    __shared__ ushort Ps[64 * LT];
    int bx = blockIdx.x;
    int c = bx & 31, h = (bx >> 5) & 15, b = bx >> 9;
    int t = threadIdx.x, lane = t & 63, w = t >> 6;
    size_t rowbase = (size_t)(b * SEQ + c * 64);
    int r = t >> 2, cc = t & 3;
    {
        const uint4* gq = (const uint4*)(qp + (rowbase + r) * D_MODEL + h * 64 + cc * 16);
        const uint4* gk = (const uint4*)(kp + (rowbase + r) * D_MODEL + h * 64 + cc * 16);
        const uint4* gv = (const uint4*)(vp + (rowbase + r) * D_MODEL + h * 64 + cc * 16);
        const uint4* gs = (const uint4*)(statesb + (size_t)bx * 4096 + t * 16);
        uint4 q0 = gq[0], q1 = gq[1];
        uint4 k0 = gk[0], k1 = gk[1];
        uint4 v0 = gv[0], v1 = gv[1];
        uint4 s0 = gs[0], s1 = gs[1];
        st16(&Qs[r * LT + cc * 16], q0, q1);
        st16(&Ks[r * LT + cc * 16], k0, k1);
        st16(&St[r * LT + cc * 16], s0, s1);  // row dv = r, dk contiguous
        us16x8 va = __builtin_bit_cast(us16x8, v0), vb = __builtin_bit_cast(us16x8, v1);
        #pragma unroll
        for (int i = 0; i < 8; i++) {
            Vt[(cc * 16 + i) * LT + r]     = va[i];
            Vt[(cc * 16 + 8 + i) * LT + r] = vb[i];
        }
    }
    __syncthreads();

    int mrel = lane & 15, q8 = (lane >> 4) * 8, quad = lane >> 4, band = w * 16;
    // A-frags from Q' band rows (shared by inter and P matmuls)
    bf16x8 af[2];
    af[0] = ld_frag(&Qs[(band + mrel) * LT + q8]);
    af[1] = ld_frag(&Qs[(band + mrel) * LT + 32 + q8]);

    // inter-chunk: O[i][dv] = sum_dk Q'[i][dk] * St[dv][dk]
    f32x4 oacc[4];
    #pragma unroll
    for (int dt = 0; dt < 4; dt++) oacc[dt] = (f32x4){0.f, 0.f, 0.f, 0.f};
    #pragma unroll
    for (int dt = 0; dt < 4; dt++)
        #pragma unroll
        for (int kk = 0; kk < 2; kk++)
            oacc[dt] = __builtin_amdgcn_mfma_f32_16x16x32_bf16(
                af[kk], ld_frag(&St[(dt * 16 + mrel) * LT + kk * 32 + q8]), oacc[dt], 0, 0, 0);

    // P = Q'K^T (only j-tiles <= wave band can be nonzero under causal mask)
    f32x4 pacc[4];
    #pragma unroll
    for (int jt = 0; jt < 4; jt++) pacc[jt] = (f32x4){0.f, 0.f, 0.f, 0.f};
    #pragma unroll
    for (int jt = 0; jt < 4; jt++) {
        if (jt <= w) {
            #pragma unroll
            for (int kk = 0; kk < 2; kk++)
                pacc[jt] = __builtin_amdgcn_mfma_f32_16x16x32_bf16(
                    af[kk], ld_frag(&Ks[(jt * 16 + mrel) * LT + kk * 32 + q8]), pacc[jt], 0, 0, 0);
        }
    }
    // mask + store P (bf16) rows i, cols j; full 64-wide band written (zeros where masked)
    #pragma unroll
    for (int jt = 0; jt < 4; jt++) {
        #pragma unroll
        for (int reg = 0; reg < 4; reg++) {
            int i = band + quad * 4 + reg;
            int j = jt * 16 + mrel;
            float val = (jt <= w && j <= i) ? pacc[jt][reg] : 0.f;
            Ps[i * LT + j] = f2bf(val);
        }
    }
    __syncthreads();

    // intra: O[i][dv] += sum_j P[i][j] * Vt[dv][j]   (k-half 1 only needed for waves 2,3)
    bf16x8 pf0 = ld_frag(&Ps[(band + mrel) * LT + q8]);
    #pragma unroll
    for (int dt = 0; dt < 4; dt++)
        oacc[dt] = __builtin_amdgcn_mfma_f32_16x16x32_bf16(
            pf0, ld_frag(&Vt[(dt * 16 + mrel) * LT + q8]), oacc[dt], 0, 0, 0);
    if (w >= 2) {
        bf16x8 pf1 = ld_frag(&Ps[(band + mrel) * LT + 32 + q8]);
        #pragma unroll
        for (int dt = 0; dt < 4; dt++)
            oacc[dt] = __builtin_amdgcn_mfma_f32_16x16x32_bf16(
                pf1, ld_frag(&Vt[(dt * 16 + mrel) * LT + 32 + q8]), oacc[dt], 0, 0, 0);
    }

    // epilogue: write bf16 attn
    #pragma unroll
    for (int dt = 0; dt < 4; dt++) {
        #pragma unroll
        for (int reg = 0; reg < 4; reg++) {
            size_t row = rowbase + band + quad * 4 + reg;
            int col = h * 64 + dt * 16 + mrel;
            attn_out[row * D_MODEL + col] = f2bf(oacc[dt][reg]);
        }
    }
}

// ---------------- host launch ----------------
extern "C" void kernel_launch(void* const* d_in, const int* in_sizes, int n_in,
                              void* d_out, int out_size, void* d_ws, size_t ws_size,
                              hipStream_t stream) {
    (void)in_sizes; (void)n_in; (void)out_size; (void)ws_size;
    const float* x  = (const float*)d_in[0];
    const float* Wq = (const float*)d_in[1];
    const float* bq = (const float*)d_in[2];
    const float* Wk = (const float*)d_in[3];
    const float* bk = (const float*)d_in[4];
    const float* Wv = (const float*)d_in[5];
    const float* bv = (const float*)d_in[6];
    const float* Wo = (const float*)d_in[7];
    const float* bo = (const float*)d_in[8];
    const float* gamma = (const float*)d_in[9];
    float* out = (float*)d_out;

    // workspace carve-up
    uint8_t* w = (uint8_t*)d_ws;
    ushort* xb  = (ushort*)w; w += (size_t)M_TOT * D_MODEL * 2;       // 8 MB; later reused as bf16 attn
    ushort* wqb = (ushort*)w; w += (size_t)D_MODEL * D_MODEL * 2;     // 2 MB
    ushort* wkb = (ushort*)w; w += (size_t)D_MODEL * D_MODEL * 2;
    ushort* wvb = (ushort*)w; w += (size_t)D_MODEL * D_MODEL * 2;
    ushort* wob = (ushort*)w; w += (size_t)D_MODEL * D_MODEL * 2;
    ushort* qb  = (ushort*)w; w += (size_t)M_TOT * D_MODEL * 2;       // 8 MB (decayed q, bf16)
    ushort* kb  = (ushort*)w; w += (size_t)M_TOT * D_MODEL * 2;
    ushort* vb  = (ushort*)w; w += (size_t)M_TOT * D_MODEL * 2;
    float*  states  = (float*)w;  w += (size_t)BATCH * NUM_HEADS * NCHUNK * 4096 * 4; // 16 MB
    ushort* statesb = (ushort*)w; w += (size_t)BATCH * NUM_HEADS * NCHUNK * 4096 * 2; // 8 MB
    float*  decay   = (float*)w;  w += (size_t)SEQ * NUM_HEADS * 4;   // 128 KB

    // casts
    cast_bf16_kernel<<<(M_TOT * D_MODEL) / 4 / 256, 256, 0, stream>>>(x, xb);
    cast_bf16_kernel<<<(D_MODEL * D_MODEL) / 4 / 256, 256, 0, stream>>>(Wq, wqb);
    cast_bf16_kernel<<<(D_MODEL * D_MODEL) / 4 / 256, 256, 0, stream>>>(Wk, wkb);
    cast_bf16_kernel<<<(D_MODEL * D_MODEL) / 4 / 256, 256, 0, stream>>>(Wv, wvb);
    cast_bf16_kernel<<<(D_MODEL * D_MODEL) / 4 / 256, 256, 0, stream>>>(Wo, wob);
    decay_kernel<<<(SEQ * NUM_HEADS) / 256, 256, 0, stream>>>(gamma, decay);

    dim3 ggrid(D_MODEL / 64, M_TOT / 64);   // (16, 64)
    gemm_bt<1><<<ggrid, 256, 0, stream>>>(xb, wqb, bq, qb, decay);   // q' = (xWq^T+bq)*gamma^i
    gemm_bt<1><<<ggrid, 256, 0, stream>>>(xb, wkb, bk, kb, nullptr);
    gemm_bt<1><<<ggrid, 256, 0, stream>>>(xb, wvb, bv, vb, nullptr);

    int nblk = BATCH * NUM_HEADS * NCHUNK;  // 1024
    chunk_kv_mfma<<<nblk, 256, 0, stream>>>(kb, vb, states);
    prefix_kernel<<<dim3(16, 32), 256, 0, stream>>>(states, statesb);
    attn_mfma<<<nblk, 256, 0, stream>>>(qb, kb, vb, statesb, xb);    // bf16 attn into xb

    gemm_bt<0><<<ggrid, 256, 0, stream>>>(xb, wob, bo, out, nullptr);
}

// Round 3
// 190.646 us; speedup vs baseline: 1.8042x; 1.1723x over previous
//
#include <hip/hip_runtime.h>
#include <hip/hip_bf16.h>

#define D_MODEL 1024
#define NUM_HEADS 16
#define HEAD_DIM 64
#define BATCH 2
#define SEQ 2048
#define M_TOT (BATCH*SEQ)      // 4096
#define CHUNK 64
#define NCHUNK (SEQ/CHUNK)     // 32
#define LT 68                  // LDS stride (ushorts) for attention tiles

typedef __attribute__((ext_vector_type(8))) short bf16x8;
typedef __attribute__((ext_vector_type(8))) unsigned short us16x8;
typedef __attribute__((ext_vector_type(4))) float f32x4;

__device__ inline ushort f2bf(float f) {
    __hip_bfloat16 h = __float2bfloat16(f);
    return __builtin_bit_cast(ushort, h);
}

__device__ inline bf16x8 ld_frag(const ushort* p) {
    struct S { uint2 a, b; };
    S s;
    s.a = *(const uint2*)p;
    s.b = *(const uint2*)(p + 4);
    return __builtin_bit_cast(bf16x8, s);
}

__device__ inline void st16(ushort* dst, uint4 a, uint4 b) {
    *(uint2*)(dst + 0)  = make_uint2(a.x, a.y);
    *(uint2*)(dst + 4)  = make_uint2(a.z, a.w);
    *(uint2*)(dst + 8)  = make_uint2(b.x, b.y);
    *(uint2*)(dst + 12) = make_uint2(b.z, b.w);
}

// async global->LDS, 16B per lane; LDS dst is wave-uniform base + lane*16
__device__ inline void load_lds16(const ushort* g, ushort* l) {
    __builtin_amdgcn_global_load_lds(
        (const __attribute__((address_space(1))) unsigned int*)g,
        (__attribute__((address_space(3))) unsigned int*)l, 16, 0, 0);
}

// ---------------- fused cast fp32 -> bf16 of x + Wq + Wk + Wv + Wo ----------------
// dst region: [xb (4M) | wq (1M) | wk (1M) | wv (1M) | wo (1M)] ushorts, contiguous.
#define XN (M_TOT * D_MODEL)              // 4194304
#define WN (D_MODEL * D_MODEL)            // 1048576
__global__ __launch_bounds__(256) void cast_all_kernel(const float* __restrict__ x,
                                                       const float* __restrict__ Wq,
                                                       const float* __restrict__ Wk,
                                                       const float* __restrict__ Wv,
                                                       const float* __restrict__ Wo,
                                                       ushort* __restrict__ dst) {
    size_t o = ((size_t)blockIdx.x * 256 + threadIdx.x) * 4;
    const float* src;
    if (o < XN)               src = x  + o;
    else if (o < XN + WN)     src = Wq + (o - XN);
    else if (o < XN + 2 * WN) src = Wk + (o - XN - WN);
    else if (o < XN + 3 * WN) src = Wv + (o - XN - 2 * (size_t)WN);
    else                      src = Wo + (o - XN - 3 * (size_t)WN);
    float4 f = *(const float4*)src;
    ushort4 u;
    u.x = f2bf(f.x); u.y = f2bf(f.y); u.z = f2bf(f.z); u.w = f2bf(f.w);
    *(ushort4*)(dst + o) = u;
}

// ---------------- decay table: decay[i*16+h] = gamma[h]^i ----------------
__global__ __launch_bounds__(256) void decay_kernel(const float* __restrict__ gamma,
                                                    float* __restrict__ decay) {
    int idx = blockIdx.x * blockDim.x + threadIdx.x;
    if (idx < SEQ * NUM_HEADS) {
        int i = idx >> 4, h = idx & 15;
        decay[idx] = powf(gamma[h], (float)i);
    }
}

// ---------------- 128x128-tile MFMA GEMM, global_load_lds staging, XOR-swizzled LDS ----
// C[m,n] = sum_k A[m,k]*Bt[n,k] + bias[n]   (K = 1024)
// grid (Ntot/128, M/128), 256 threads = 4 waves in 2x2; each wave does 64x64 (4x4 frags).
// NBUF=3: Bt is [3072][1024] (Wq|Wk|Wv); outputs bf16 into o0/o1/o2 (each [M][1024]);
//         decay applied to buffer 0. NBUF=1: single fp32 output o0 with bias b0.
template <int NBUF, int OUT_BF16>
__global__ __launch_bounds__(256) void gemm128(const ushort* __restrict__ A,
                                               const ushort* __restrict__ Bt,
                                               const float* __restrict__ b0,
                                               const float* __restrict__ b1,
                                               const float* __restrict__ b2,
                                               void* __restrict__ o0,
                                               void* __restrict__ o1,
                                               void* __restrict__ o2,
                                               const float* __restrict__ decay) {
    const int K = 1024;
    __shared__ ushort lds_a[128 * 64];   // 16 KB, row-major, chunk-col XOR-swizzled
    __shared__ ushort lds_b[128 * 64];
    int t = threadIdx.x;
    int lane = t & 63, w = t >> 6;
    int bm = blockIdx.y * 128, bn = blockIdx.x * 128;
    int wm = (w >> 1) * 64, wn = (w & 1) * 64;

    // staging lane mapping: lane -> LDS chunk (row = lane>>3 within 8-row slab, col = lane&7)
    // LDS(row,c) holds global chunk (row, c ^ (row&7)) -> lane loads gcol = (lane&7)^(lane>>3 &7)
    int lr = lane >> 3, lc = lane & 7;
    int gcol = lc ^ (lr & 7);
    const ushort* aBase = A  + (size_t)(bm + w * 32 + lr) * K + gcol * 8;
    const ushort* bBase = Bt + (size_t)(bn + w * 32 + lr) * K + gcol * 8;
    ushort* aLds = &lds_a[(w * 32) * 64];
    ushort* bLds = &lds_b[(w * 32) * 64];

    f32x4 acc[4][4];
    #pragma unroll
    for (int i = 0; i < 4; i++)
        #pragma unroll
        for (int j = 0; j < 4; j++)
            acc[i][j] = (f32x4){0.f, 0.f, 0.f, 0.f};

    int mrel = lane & 15, kq = lane >> 4;

    for (int k0 = 0; k0 < K; k0 += 64) {
        #pragma unroll
        for (int q = 0; q < 4; q++) {
            load_lds16(aBase + (size_t)q * 8 * K + k0, aLds + q * 512);
            load_lds16(bBase + (size_t)q * 8 * K + k0, bLds + q * 512);
        }
        __syncthreads();
        #pragma unroll
        for (int s = 0; s < 2; s++) {
            bf16x8 af[4], bfv[4];
            #pragma unroll
            for (int i = 0; i < 4; i++) {
                int row = wm + i * 16 + mrel;
                af[i] = ld_frag(&lds_a[row * 64 + (((s * 4 + kq) ^ (row & 7)) * 8)]);
            }
            #pragma unroll
            for (int j = 0; j < 4; j++) {
                int row = wn + j * 16 + mrel;
                bfv[j] = ld_frag(&lds_b[row * 64 + (((s * 4 + kq) ^ (row & 7)) * 8)]);
            }
            #pragma unroll
            for (int i = 0; i < 4; i++)
                #pragma unroll
                for (int j = 0; j < 4; j++)
                    acc[i][j] = __builtin_amdgcn_mfma_f32_16x16x32_bf16(af[i], bfv[j], acc[i][j], 0, 0, 0);
        }
        __syncthreads();
    }

    // epilogue. C/D layout: col = lane&15, row = (lane>>4)*4 + reg
    int quad = lane >> 4;
    int buf = (NBUF == 3) ? (bn >> 10) : 0;
    const float* bias = (buf == 0) ? b0 : (buf == 1) ? b1 : b2;
    void* dstv = (buf == 0) ? o0 : (buf == 1) ? o1 : o2;
    int cbase = ((NBUF == 3) ? (bn & 1023) : bn) + wn;
    #pragma unroll
    for (int j = 0; j < 4; j++) {
        int cl = cbase + j * 16 + mrel;
        float bv = bias[cl];
        #pragma unroll
        for (int i = 0; i < 4; i++) {
            #pragma unroll
            for (int reg = 0; reg < 4; reg++) {
                int row = bm + wm + i * 16 + quad * 4 + reg;
                float v = acc[i][j][reg] + bv;
                if (NBUF == 3 && buf == 0)
                    v *= decay[(row & (SEQ - 1)) * 16 + (cl >> 6)];
                if (OUT_BF16)
                    ((ushort*)dstv)[(size_t)row * 1024 + cl] = f2bf(v);
                else
                    ((float*)dstv)[(size_t)row * 1024 + cl] = v;
            }
        }
    }
}

// ---------------- per-chunk KV state (MFMA): St[dv][dk] = sum_j V[j][dv]*K[j][dk] ----------------
__global__ __launch_bounds__(256) void chunk_kv_mfma(const ushort* __restrict__ kp,
                                                     const ushort* __restrict__ vp,
                                                     float* __restrict__ states) {
    __shared__ ushort Kt[64 * LT];
    __shared__ ushort Vt[64 * LT];
    int bx = blockIdx.x;
    int c = bx & 31, h = (bx >> 5) & 15, b = bx >> 9;
    int t = threadIdx.x, lane = t & 63, w = t >> 6;
    size_t rowbase = (size_t)(b * SEQ + c * 64);
    int r = t >> 2, cc = t & 3;
    const uint4* gk = (const uint4*)(kp + (rowbase + r) * D_MODEL + h * 64 + cc * 16);
    const uint4* gv = (const uint4*)(vp + (rowbase + r) * D_MODEL + h * 64 + cc * 16);
    uint4 k0 = gk[0], k1 = gk[1], v0 = gv[0], v1 = gv[1];
    {
        us16x8 ka = __builtin_bit_cast(us16x8, k0), kb = __builtin_bit_cast(us16x8, k1);
        us16x8 va = __builtin_bit_cast(us16x8, v0), vb = __builtin_bit_cast(us16x8, v1);
        #pragma unroll
        for (int i = 0; i < 8; i++) {
            Kt[(cc * 16 + i) * LT + r]     = ka[i];
            Kt[(cc * 16 + 8 + i) * LT + r] = kb[i];
            Vt[(cc * 16 + i) * LT + r]     = va[i];
            Vt[(cc * 16 + 8 + i) * LT + r] = vb[i];
        }
    }
    __syncthreads();
    int mrel = lane & 15, q8 = (lane >> 4) * 8, band = w * 16;
    bf16x8 af[2];
    af[0] = ld_frag(&Vt[(band + mrel) * LT + q8]);
    af[1] = ld_frag(&Vt[(band + mrel) * LT + 32 + q8]);
    f32x4 acc[4];
    #pragma unroll
    for (int dt = 0; dt < 4; dt++) acc[dt] = (f32x4){0.f, 0.f, 0.f, 0.f};
    #pragma unroll
    for (int dt = 0; dt < 4; dt++)
        #pragma unroll
        for (int kk = 0; kk < 2; kk++)
            acc[dt] = __builtin_amdgcn_mfma_f32_16x16x32_bf16(
                af[kk], ld_frag(&Kt[(dt * 16 + mrel) * LT + kk * 32 + q8]), acc[dt], 0, 0, 0);
    int quad = lane >> 4;
    float* sp = states + (size_t)bx * 4096;
    #pragma unroll
    for (int dt = 0; dt < 4; dt++)
        #pragma unroll
        for (int reg = 0; reg < 4; reg++)
            sp[(band + quad * 4 + reg) * 64 + dt * 16 + mrel] = acc[dt][reg];
}

// ---------------- exclusive prefix over chunks -> bf16 states ----------------
__global__ __launch_bounds__(256) void prefix_kernel(const float* __restrict__ states,
                                                     ushort* __restrict__ statesb) {
    int bh = blockIdx.y;
    int e = blockIdx.x * 256 + threadIdx.x;
    const float* src = states + (size_t)bh * NCHUNK * 4096 + e;
    ushort* dst = statesb + (size_t)bh * NCHUNK * 4096 + e;
    float run = 0.f;
    for (int cb = 0; cb < NCHUNK; cb += 8) {
        float vals[8];
        #pragma unroll
        for (int u = 0; u < 8; u++) vals[u] = src[(size_t)(cb + u) * 4096];
        #pragma unroll
        for (int u = 0; u < 8; u++) {
            dst[(size_t)(cb + u) * 4096] = f2bf(run);
            run += vals[u];
        }
    }
}

// ---------------- per-chunk attention (MFMA): O = Q'·S^T + causal(Q'K^T)·V ----------------
__global__ __launch_bounds__(256) void attn_mfma(const ushort* __restrict__ qp,
                                                 const ushort* __restrict__ kp,
                                                 const ushort* __restrict__ vp,
                                                 const ushort* __restrict__ statesb,
                                                 ushort* __restrict__ attn_out) {
    __shared__ ushort Qs[64 * LT];
    __shared__ ushort Ks[64 * LT];
    __shared__ ushort Vt[64 * LT];
    __shared__ ushort St[64 * LT];
    __shared__ ushort Ps[64 * LT];
    int bx = blockIdx.x;
    int c = bx & 31, h = (bx >> 5) & 15, b = bx >> 9;
    int t = threadIdx.x, lane = t & 63, w = t >> 6;
    size_t rowbase = (size_t)(b * SEQ + c * 64);
    int r = t >> 2, cc = t & 3;
    {
        const uint4* gq = (const uint4*)(qp + (rowbase + r) * D_MODEL + h * 64 + cc * 16);
        const uint4* gk = (const uint4*)(kp + (rowbase + r) * D_MODEL + h * 64 + cc * 16);
        const uint4* gv = (const uint4*)(vp + (rowbase + r) * D_MODEL + h * 64 + cc * 16);
        const uint4* gs = (const uint4*)(statesb + (size_t)bx * 4096 + t * 16);
        uint4 q0 = gq[0], q1 = gq[1];
        uint4 k0 = gk[0], k1 = gk[1];
        uint4 v0 = gv[0], v1 = gv[1];
        uint4 s0 = gs[0], s1 = gs[1];
        st16(&Qs[r * LT + cc * 16], q0, q1);
        st16(&Ks[r * LT + cc * 16], k0, k1);
        st16(&St[r * LT + cc * 16], s0, s1);
        us16x8 va = __builtin_bit_cast(us16x8, v0), vb = __builtin_bit_cast(us16x8, v1);
        #pragma unroll
        for (int i = 0; i < 8; i++) {
            Vt[(cc * 16 + i) * LT + r]     = va[i];
            Vt[(cc * 16 + 8 + i) * LT + r] = vb[i];
        }
    }
    __syncthreads();

    int mrel = lane & 15, q8 = (lane >> 4) * 8, quad = lane >> 4, band = w * 16;
    bf16x8 af[2];
    af[0] = ld_frag(&Qs[(band + mrel) * LT + q8]);
    af[1] = ld_frag(&Qs[(band + mrel) * LT + 32 + q8]);

    f32x4 oacc[4];
    #pragma unroll
    for (int dt = 0; dt < 4; dt++) oacc[dt] = (f32x4){0.f, 0.f, 0.f, 0.f};
    #pragma unroll
    for (int dt = 0; dt < 4; dt++)
        #pragma unroll
        for (int kk = 0; kk < 2; kk++)
            oacc[dt] = __builtin_amdgcn_mfma_f32_16x16x32_bf16(
                af[kk], ld_frag(&St[(dt * 16 + mrel) * LT + kk * 32 + q8]), oacc[dt], 0, 0, 0);

    f32x4 pacc[4];
    #pragma unroll
    for (int jt = 0; jt < 4; jt++) pacc[jt] = (f32x4){0.f, 0.f, 0.f, 0.f};
    #pragma unroll
    for (int jt = 0; jt < 4; jt++) {
        if (jt <= w) {
            #pragma unroll
            for (int kk = 0; kk < 2; kk++)
                pacc[jt] = __builtin_amdgcn_mfma_f32_16x16x32_bf16(
                    af[kk], ld_frag(&Ks[(jt * 16 + mrel) * LT + kk * 32 + q8]), pacc[jt], 0, 0, 0);
        }
    }
    #pragma unroll
    for (int jt = 0; jt < 4; jt++) {
        #pragma unroll
        for (int reg = 0; reg < 4; reg++) {
            int i = band + quad * 4 + reg;
            int j = jt * 16 + mrel;
            float val = (jt <= w && j <= i) ? pacc[jt][reg] : 0.f;
            Ps[i * LT + j] = f2bf(val);
        }
    }
    __syncthreads();

    bf16x8 pf0 = ld_frag(&Ps[(band + mrel) * LT + q8]);
    #pragma unroll
    for (int dt = 0; dt < 4; dt++)
        oacc[dt] = __builtin_amdgcn_mfma_f32_16x16x32_bf16(
            pf0, ld_frag(&Vt[(dt * 16 + mrel) * LT + q8]), oacc[dt], 0, 0, 0);
    if (w >= 2) {
        bf16x8 pf1 = ld_frag(&Ps[(band + mrel) * LT + 32 + q8]);
        #pragma unroll
        for (int dt = 0; dt < 4; dt++)
            oacc[dt] = __builtin_amdgcn_mfma_f32_16x16x32_bf16(
                pf1, ld_frag(&Vt[(dt * 16 + mrel) * LT + 32 + q8]), oacc[dt], 0, 0, 0);
    }

    #pragma unroll
    for (int dt = 0; dt < 4; dt++) {
        #pragma unroll
        for (int reg = 0; reg < 4; reg++) {
            size_t row = rowbase + band + quad * 4 + reg;
            int col = h * 64 + dt * 16 + mrel;
            attn_out[row * D_MODEL + col] = f2bf(oacc[dt][reg]);
        }
    }
}

// ---------------- host launch ----------------
extern "C" void kernel_launch(void* const* d_in, const int* in_sizes, int n_in,
                              void* d_out, int out_size, void* d_ws, size_t ws_size,
                              hipStream_t stream) {
    (void)in_sizes; (void)n_in; (void)out_size; (void)ws_size;
    const float* x  = (const float*)d_in[0];
    const float* Wq = (const float*)d_in[1];
    const float* bq = (const float*)d_in[2];
    const float* Wk = (const float*)d_in[3];
    const float* bk = (const float*)d_in[4];
    const float* Wv = (const float*)d_in[5];
    const float* bv = (const float*)d_in[6];
    const float* Wo = (const float*)d_in[7];
    const float* bo = (const float*)d_in[8];
    const float* gamma = (const float*)d_in[9];
    float* out = (float*)d_out;

    // workspace carve-up. bf16 region [xb | wqkv | wo] must be contiguous for cast_all.
    uint8_t* w = (uint8_t*)d_ws;
    ushort* xb    = (ushort*)w; w += (size_t)XN * 2;            // 8 MB; reused as bf16 attn later
    ushort* wqkvb = (ushort*)w; w += (size_t)3 * WN * 2;        // 6 MB
    ushort* wob   = (ushort*)w; w += (size_t)WN * 2;            // 2 MB
    ushort* qb  = (ushort*)w; w += (size_t)XN * 2;              // 8 MB
    ushort* kb  = (ushort*)w; w += (size_t)XN * 2;
    ushort* vb  = (ushort*)w; w += (size_t)XN * 2;
    float*  states  = (float*)w;  w += (size_t)BATCH * NUM_HEADS * NCHUNK * 4096 * 4; // 16 MB
    ushort* statesb = (ushort*)w; w += (size_t)BATCH * NUM_HEADS * NCHUNK * 4096 * 2; // 8 MB
    float*  decay   = (float*)w;  w += (size_t)SEQ * NUM_HEADS * 4;

    cast_all_kernel<<<(XN + 4 * WN) / 4 / 256, 256, 0, stream>>>(x, Wq, Wk, Wv, Wo, xb);
    decay_kernel<<<(SEQ * NUM_HEADS) / 256, 256, 0, stream>>>(gamma, decay);

    // fused QKV projection: Bt = [Wq|Wk|Wv] (3072 x 1024), bf16 out, decay folded into q
    gemm128<3, 1><<<dim3(3072 / 128, M_TOT / 128), 256, 0, stream>>>(
        xb, wqkvb, bq, bk, bv, qb, kb, vb, decay);

    int nblk = BATCH * NUM_HEADS * NCHUNK;  // 1024
    chunk_kv_mfma<<<nblk, 256, 0, stream>>>(kb, vb, states);
    prefix_kernel<<<dim3(16, 32), 256, 0, stream>>>(states, statesb);
    attn_mfma<<<nblk, 256, 0, stream>>>(qb, kb, vb, statesb, xb);    // bf16 attn into xb

    // output projection: fp32 out
    gemm128<1, 0><<<dim3(1024 / 128, M_TOT / 128), 256, 0, stream>>>(
        xb, wob, bo, nullptr, nullptr, out, nullptr, nullptr, nullptr);
}